// Round 1
// baseline (61.016 us; speedup 1.0000x reference)
//
#include <hip/hip_runtime.h>
#include <math.h>

// Problem constants (from reference): eps_t, y_t are (256, 24, 4096) f32.
#define BATCH_SZ   256
#define D_EVENT    (24 * 4096)                  // 98304
#define N_TOTAL    (BATCH_SZ * D_EVENT)         // 25,165,824 (divisible by 4)

// Grid-stride masked sum-of-squares reduction, float4-vectorized.
__global__ void mgd_reduce_kernel(const float4* __restrict__ eps,
                                  const float4* __restrict__ y,
                                  float* __restrict__ acc, int n4) {
    int tid    = blockIdx.x * blockDim.x + threadIdx.x;
    int stride = gridDim.x * blockDim.x;
    float sum = 0.0f;
    for (int i = tid; i < n4; i += stride) {
        float4 e = eps[i];
        float4 g = y[i];
        // mask = (y != 0.0): note -0.0 == 0.0 in IEEE, matches reference.
        if (g.x != 0.0f) sum = fmaf(e.x, e.x, sum);
        if (g.y != 0.0f) sum = fmaf(e.y, e.y, sum);
        if (g.z != 0.0f) sum = fmaf(e.z, e.z, sum);
        if (g.w != 0.0f) sum = fmaf(e.w, e.w, sum);
    }
    // Wave-64 shuffle reduction.
    #pragma unroll
    for (int off = 32; off > 0; off >>= 1)
        sum += __shfl_down(sum, off, 64);
    __shared__ float lds[4];                    // 256 threads / 64 = 4 waves
    int lane = threadIdx.x & 63;
    int wave = threadIdx.x >> 6;
    if (lane == 0) lds[wave] = sum;
    __syncthreads();
    if (threadIdx.x == 0) {
        float s = lds[0] + lds[1] + lds[2] + lds[3];
        atomicAdd(acc, s);                      // device-scope by default
    }
}

// Single-thread finalize: softplus + closed-form loss.
__global__ void mgd_finalize_kernel(const float* __restrict__ acc,
                                    const float* __restrict__ sigma,
                                    float* __restrict__ out) {
    float sg = sigma[0];
    // numerically stable softplus
    float s = fmaxf(sg, 0.0f) + log1pf(expf(-fabsf(sg)));
    const float LOG_2PI = 1.8378770664093453f;
    float quad_mean = acc[0] / ((float)BATCH_SZ * s);
    out[0] = 0.5f * (quad_mean + (float)D_EVENT * (LOG_2PI + logf(s)));
}

extern "C" void kernel_launch(void* const* d_in, const int* in_sizes, int n_in,
                              void* d_out, int out_size, void* d_ws, size_t ws_size,
                              hipStream_t stream) {
    const float4* eps   = (const float4*)d_in[0];
    const float4* y     = (const float4*)d_in[1];
    const float*  sigma = (const float*)d_in[2];
    float* out = (float*)d_out;
    float* acc = (float*)d_ws;

    // Workspace is poisoned (0xAA) and NOT re-poisoned between replays:
    // zero the accumulator ourselves, async on the capture stream.
    hipMemsetAsync(acc, 0, sizeof(float), stream);

    const int n4 = N_TOTAL / 4;                 // 6,291,456 float4 elements
    const int block = 256;
    const int grid  = 2048;                     // 256 CU × 8 blocks, grid-stride

    mgd_reduce_kernel<<<grid, block, 0, stream>>>(eps, y, acc, n4);
    mgd_finalize_kernel<<<1, 1, 0, stream>>>(acc, sigma, out);
}

// Round 2
// 48.680 us; speedup vs baseline: 1.2534x; 1.2534x over previous
//
#include <hip/hip_runtime.h>
#include <math.h>

// Problem constants (from reference): eps_t, y_t are (256, 24, 4096) f32.
#define BATCH_SZ   256
#define D_EVENT    (24 * 4096)                  // 98304
#define N_TOTAL    (BATCH_SZ * D_EVENT)         // 25,165,824

#define BLOCK      256
#define GRID       2048
#define STRIDE     (GRID * BLOCK)               // 524,288 threads
#define N4         (N_TOTAL / 4)                // 6,291,456 float4
#define ITERS      (N4 / STRIDE)                // 12, exact — no remainder

// Masked sum-of-squares reduction; unroll x4, 8 loads in flight,
// 4 independent accumulators to break the loop-carried latency chain.
__global__ void __launch_bounds__(BLOCK)
mgd_reduce_kernel(const float4* __restrict__ eps,
                  const float4* __restrict__ y,
                  float* __restrict__ acc) {
    int tid = blockIdx.x * BLOCK + threadIdx.x;
    float s0 = 0.0f, s1 = 0.0f, s2 = 0.0f, s3 = 0.0f;

    #pragma unroll
    for (int k = 0; k < ITERS; k += 4) {
        // Issue all 8 loads before any use — max memory-level parallelism.
        float4 e0 = eps[tid + (k + 0) * STRIDE];
        float4 e1 = eps[tid + (k + 1) * STRIDE];
        float4 e2 = eps[tid + (k + 2) * STRIDE];
        float4 e3 = eps[tid + (k + 3) * STRIDE];
        float4 g0 = y  [tid + (k + 0) * STRIDE];
        float4 g1 = y  [tid + (k + 1) * STRIDE];
        float4 g2 = y  [tid + (k + 2) * STRIDE];
        float4 g3 = y  [tid + (k + 3) * STRIDE];

        // Branchless mask: v_cmp + v_cndmask + v_fma per element.
        float m;
        m = (g0.x != 0.0f) ? e0.x : 0.0f; s0 = fmaf(m, m, s0);
        m = (g0.y != 0.0f) ? e0.y : 0.0f; s0 = fmaf(m, m, s0);
        m = (g0.z != 0.0f) ? e0.z : 0.0f; s0 = fmaf(m, m, s0);
        m = (g0.w != 0.0f) ? e0.w : 0.0f; s0 = fmaf(m, m, s0);
        m = (g1.x != 0.0f) ? e1.x : 0.0f; s1 = fmaf(m, m, s1);
        m = (g1.y != 0.0f) ? e1.y : 0.0f; s1 = fmaf(m, m, s1);
        m = (g1.z != 0.0f) ? e1.z : 0.0f; s1 = fmaf(m, m, s1);
        m = (g1.w != 0.0f) ? e1.w : 0.0f; s1 = fmaf(m, m, s1);
        m = (g2.x != 0.0f) ? e2.x : 0.0f; s2 = fmaf(m, m, s2);
        m = (g2.y != 0.0f) ? e2.y : 0.0f; s2 = fmaf(m, m, s2);
        m = (g2.z != 0.0f) ? e2.z : 0.0f; s2 = fmaf(m, m, s2);
        m = (g2.w != 0.0f) ? e2.w : 0.0f; s2 = fmaf(m, m, s2);
        m = (g3.x != 0.0f) ? e3.x : 0.0f; s3 = fmaf(m, m, s3);
        m = (g3.y != 0.0f) ? e3.y : 0.0f; s3 = fmaf(m, m, s3);
        m = (g3.z != 0.0f) ? e3.z : 0.0f; s3 = fmaf(m, m, s3);
        m = (g3.w != 0.0f) ? e3.w : 0.0f; s3 = fmaf(m, m, s3);
    }
    float sum = (s0 + s1) + (s2 + s3);

    // Wave-64 shuffle reduction.
    #pragma unroll
    for (int off = 32; off > 0; off >>= 1)
        sum += __shfl_down(sum, off, 64);
    __shared__ float lds[BLOCK / 64];
    int lane = threadIdx.x & 63;
    int wave = threadIdx.x >> 6;
    if (lane == 0) lds[wave] = sum;
    __syncthreads();
    if (threadIdx.x == 0) {
        float s = (lds[0] + lds[1]) + (lds[2] + lds[3]);
        atomicAdd(acc, s);                      // device-scope by default
    }
}

// Single-thread finalize: softplus + closed-form loss.
__global__ void mgd_finalize_kernel(const float* __restrict__ acc,
                                    const float* __restrict__ sigma,
                                    float* __restrict__ out) {
    float sg = sigma[0];
    float s = fmaxf(sg, 0.0f) + log1pf(expf(-fabsf(sg)));  // stable softplus
    const float LOG_2PI = 1.8378770664093453f;
    float quad_mean = acc[0] / ((float)BATCH_SZ * s);
    out[0] = 0.5f * (quad_mean + (float)D_EVENT * (LOG_2PI + logf(s)));
}

extern "C" void kernel_launch(void* const* d_in, const int* in_sizes, int n_in,
                              void* d_out, int out_size, void* d_ws, size_t ws_size,
                              hipStream_t stream) {
    const float4* eps   = (const float4*)d_in[0];
    const float4* y     = (const float4*)d_in[1];
    const float*  sigma = (const float*)d_in[2];
    float* out = (float*)d_out;
    float* acc = (float*)d_ws;

    // d_ws is poisoned once (0xAA) and never re-poisoned: zero it each call.
    hipMemsetAsync(acc, 0, sizeof(float), stream);

    mgd_reduce_kernel<<<GRID, BLOCK, 0, stream>>>(eps, y, acc);
    mgd_finalize_kernel<<<1, 1, 0, stream>>>(acc, sigma, out);
}